// Round 13
// baseline (303.022 us; speedup 1.0000x reference)
//
#include <hip/hip_runtime.h>
#include <hip/hip_fp16.h>
#include <math.h>

#define N_NODES 50000
#define N_EDGES 800000
#define ET (N_EDGES + N_NODES)   // edges + self-loops
#define IN_DIM 128
#define HID 64
#define HEADS 4
#define C1 (HEADS * HID)         // 256
#define OUT_DIM 128
#define NEG_SLOPE 0.2f
#define MTILES 3125              // 50000 / 16 row-tiles
#define G1GRP 782                // ceil(MTILES/4) gemm1 tile groups
#define SCAN_B 1024
#define NSCB 49                  // ceil(50000/1024)
#define HB 64                    // histogram edge-segments
#define EPB (N_EDGES / HB)       // 12500 edges per segment (EPB/4 = 3125)
#define NQ (N_NODES / 4)         // 12500 nodes per quarter

typedef _Float16 h8 __attribute__((ext_vector_type(8)));
typedef float f4 __attribute__((ext_vector_type(4)));
typedef unsigned short u16;

__device__ __forceinline__ float leaky(float v) { return fmaxf(v, NEG_SLOPE * v); }
__device__ __forceinline__ float elu(float v) { return v > 0.0f ? v : expm1f(v); }

// One v_fma_mix_f32 per feature: acc.f32 += h.f16 * w.f32 (no extract/convert insts)
__device__ __forceinline__ void fma_mix8(float* acc, h8 v, float w) {
    union { h8 h; int i[4]; } u; u.h = v;
#pragma unroll
    for (int k = 0; k < 4; ++k) {
        asm("v_fma_mix_f32 %0, %1, %2, %0 op_sel:[0,0,0] op_sel_hi:[1,0,0]"
            : "+v"(acc[2 * k]) : "v"(u.i[k]), "v"(w));
        asm("v_fma_mix_f32 %0, %1, %2, %0 op_sel:[1,0,0] op_sel_hi:[1,0,0]"
            : "+v"(acc[2 * k + 1]) : "v"(u.i[k]), "v"(w));
    }
}

// ====== hist: 256 blocks = 64 edge-segments x 4 node-quarters, 25 KB LDS each ====
// 4x the parallelism of the r11 version (which ran 64 blocks with a serial 2-pass
// node loop — the suspected hidden pole). Each block: zero 6250 u32, one pass over
// its segment's 12.5k dst (int4 loads, 4 indep LDS atomics), dump its quarter row.
// Outputs (cnt_mat[64][50k], lrank16) identical to before; scan/scatter unchanged.
__global__ __launch_bounds__(256) void hist_kernel(
        const float* __restrict__ W1, const float* __restrict__ W2,
        __half* __restrict__ w1t, __half* __restrict__ w2t,
        const int* __restrict__ dst, u16* __restrict__ cnt_mat,
        u16* __restrict__ lrank16) {
    __shared__ unsigned pk[NQ / 2];   // 6250 u32 = 25 KB (12.5k nodes, 2 per u32)
    const int b = blockIdx.x >> 2;    // edge segment
    const int qd = blockIdx.x & 3;    // node quarter
    const int t = threadIdx.x;
    {   // weight transpose spread over the 256 blocks (one element per thread)
        int i = blockIdx.x * 256 + t;
        if (i < IN_DIM * C1) {
            int k1 = i >> 8, n1 = i & 255;
            w1t[n1 * IN_DIM + k1] = __float2half(W1[i]);
            int k2 = i >> 7, n2 = i & 127;
            w2t[n2 * C1 + k2] = __float2half(W2[i]);
        }
    }
    const int e0 = b * EPB;
    const int nbase = qd * NQ;
    for (int i = t; i < NQ / 2; i += 256) pk[i] = 0;
    __syncthreads();
    const int4* d4p = (const int4*)(dst + e0);
    for (int k4 = t; k4 < EPB / 4; k4 += 256) {   // 13 iterations
        int4 d4 = d4p[k4];
        int dd0 = d4.x - nbase, dd1 = d4.y - nbase;
        int dd2 = d4.z - nbase, dd3 = d4.w - nbase;
        if ((unsigned)dd0 < (unsigned)NQ) {
            unsigned r = atomicAdd(&pk[dd0 >> 1], (dd0 & 1) ? 65536u : 1u);
            lrank16[e0 + k4 * 4 + 0] = (u16)((dd0 & 1) ? (r >> 16) : (r & 0xffffu));
        }
        if ((unsigned)dd1 < (unsigned)NQ) {
            unsigned r = atomicAdd(&pk[dd1 >> 1], (dd1 & 1) ? 65536u : 1u);
            lrank16[e0 + k4 * 4 + 1] = (u16)((dd1 & 1) ? (r >> 16) : (r & 0xffffu));
        }
        if ((unsigned)dd2 < (unsigned)NQ) {
            unsigned r = atomicAdd(&pk[dd2 >> 1], (dd2 & 1) ? 65536u : 1u);
            lrank16[e0 + k4 * 4 + 2] = (u16)((dd2 & 1) ? (r >> 16) : (r & 0xffffu));
        }
        if ((unsigned)dd3 < (unsigned)NQ) {
            unsigned r = atomicAdd(&pk[dd3 >> 1], (dd3 & 1) ? 65536u : 1u);
            lrank16[e0 + k4 * 4 + 3] = (u16)((dd3 & 1) ? (r >> 16) : (r & 0xffffu));
        }
    }
    __syncthreads();
    // dump this (segment, quarter)'s counts: u16 pair layout, 4-B aligned
    unsigned* crow = (unsigned*)(cnt_mat + (size_t)b * N_NODES + nbase);
    for (int i = t; i < NQ / 2; i += 256) crow[i] = pk[i];
}

// ====== CSR scan: per-node total over 64 block-counts + exclusive block offsets ====
__global__ void scan_local(const u16* __restrict__ cnt_mat, u16* __restrict__ boff,
                           int* __restrict__ lscan, int* __restrict__ bsum) {
    __shared__ int wsum[16];
    const int t = threadIdx.x, lane = t & 63, wv = t >> 6;
    int idx = blockIdx.x * SCAN_B + t;
    int run = 0;
    if (idx < N_NODES) {
#pragma unroll 8
        for (int b = 0; b < HB; ++b) {            // coalesced per-b column walk
            u16 c = cnt_mat[(size_t)b * N_NODES + idx];
            boff[(size_t)b * N_NODES + idx] = (u16)run;
            run += c;
        }
    }
    int v = (idx < N_NODES) ? run + 1 : 0;        // +1 = self-loop
    int sc = v;
#pragma unroll
    for (int o = 1; o < 64; o <<= 1) {
        int u = __shfl_up(sc, o);
        if (lane >= o) sc += u;
    }
    if (lane == 63) wsum[wv] = sc;
    __syncthreads();
    if (t == 0) {
        int run2 = 0;
#pragma unroll
        for (int w = 0; w < 16; ++w) { int s = wsum[w]; wsum[w] = run2; run2 += s; }
        bsum[blockIdx.x] = run2;
    }
    __syncthreads();
    if (idx < N_NODES) lscan[idx] = sc + wsum[wv];  // inclusive within block
}

// ====== scan_final with inlined bsum prefix ======
__global__ void scan_final(const int* __restrict__ lscan, const int* __restrict__ bsum,
                           int* __restrict__ rp) {
    __shared__ int base;
    if (threadIdx.x == 0) {
        int s = 0;
        for (int b = 0; b < blockIdx.x; ++b) s += bsum[b];   // <= 48 loads
        base = s;
    }
    __syncthreads();
    int idx = blockIdx.x * SCAN_B + threadIdx.x;
    if (idx == 0) rp[0] = 0;
    if (idx >= N_NODES) return;
    rp[idx + 1] = lscan[idx] + base;
}

// ========= FUSED: atomic-free scatter || GEMM1, with grid-base for 2-way split ====
__global__ __launch_bounds__(256) void gemm1_scatter(
        const float* __restrict__ x, const __half* __restrict__ w1t,
        const float* __restrict__ aws, const float* __restrict__ awd,
        __half* __restrict__ hpm, float* __restrict__ as1m, float* __restrict__ ad1m,
        const int* __restrict__ src, const int* __restrict__ dst,
        const u16* __restrict__ lrank16, const u16* __restrict__ boff,
        const int* __restrict__ rp, u16* __restrict__ cs16, int gbase) {
    const int vb = blockIdx.x + gbase;
    const int q9 = vb / 9, r9 = vb % 9;
    if (r9 >= 4) {
        // ---- scatter role ----
        int si = q9 * 5 + (r9 - 4);
        int tid = si * 256 + threadIdx.x;
        if (tid < N_EDGES / 4) {
            const int b = tid / (EPB / 4);        // 4 edges of one hist segment
            const u16* bo = boff + (size_t)b * N_NODES;
            int4 s4 = ((const int4*)src)[tid];
            int4 d4 = ((const int4*)dst)[tid];
            ushort4 r4 = ((const ushort4*)lrank16)[tid];
            cs16[rp[d4.x] + (int)bo[d4.x] + (int)r4.x] = (u16)s4.x;
            cs16[rp[d4.y] + (int)bo[d4.y] + (int)r4.y] = (u16)s4.y;
            cs16[rp[d4.z] + (int)bo[d4.z] + (int)r4.z] = (u16)s4.z;
            cs16[rp[d4.w] + (int)bo[d4.w] + (int)r4.w] = (u16)s4.w;
        } else {
            int d = tid - N_EDGES / 4;
            if (d < N_NODES) cs16[rp[d + 1] - 1] = (u16)d;   // self-loop in last slot
        }
        return;
    }
    // ---- gemm1 role ----
    const int g = q9 * 4 + r9;
    const int tile = g * 4 + (threadIdx.x >> 6);
    if (tile >= MTILES) return;
    const int lane = threadIdx.x & 63;
    const int m0 = tile * 16, lm = lane & 15, lq = lane >> 4;
    h8 afrag[4];
    const float4* xrow = (const float4*)(x + (size_t)(m0 + lm) * IN_DIM + lq * 8);
#pragma unroll
    for (int kt = 0; kt < 4; ++kt) {
        float4 a = xrow[kt * 8];
        float4 b = xrow[kt * 8 + 1];
        union { h8 v; __half2 p[4]; } u;
        u.p[0] = __floats2half2_rn(a.x, a.y);
        u.p[1] = __floats2half2_rn(a.z, a.w);
        u.p[2] = __floats2half2_rn(b.x, b.y);
        u.p[3] = __floats2half2_rn(b.z, b.w);
        afrag[kt] = u.v;
    }
    f4 acc[16];
#pragma unroll
    for (int nt = 0; nt < 16; ++nt) acc[nt] = (f4){0.f, 0.f, 0.f, 0.f};
#pragma unroll
    for (int nt = 0; nt < 16; ++nt) {
        const h8* brow = (const h8*)(w1t + (size_t)(nt * 16 + lm) * IN_DIM + lq * 8);
#pragma unroll
        for (int kt = 0; kt < 4; ++kt)
            acc[nt] = __builtin_amdgcn_mfma_f32_16x16x32_f16(afrag[kt], brow[kt * 4],
                                                             acc[nt], 0, 0, 0);
    }
    float sS[4][4] = {{0.f}}, sD[4][4] = {{0.f}};
#pragma unroll
    for (int nt = 0; nt < 16; ++nt) {
        int col = nt * 16 + lm;
        float wa = aws[col], wd = awd[col];
        int hd = nt >> 2;           // head = col >> 6
        int pr = nt >> 3;           // pair = col >> 7
        int cip = col & 127;        // col within pair row
#pragma unroll
        for (int r = 0; r < 4; ++r) {
            float v = acc[nt][r];
            hpm[((size_t)pr * N_NODES + (m0 + lq * 4 + r)) * 128 + cip] = __float2half(v);
            sS[hd][r] += v * wa;
            sD[hd][r] += v * wd;
        }
    }
#pragma unroll
    for (int o = 1; o < 16; o <<= 1) {
#pragma unroll
        for (int hd = 0; hd < 4; ++hd)
#pragma unroll
            for (int r = 0; r < 4; ++r) {
                sS[hd][r] += __shfl_xor(sS[hd][r], o);
                sD[hd][r] += __shfl_xor(sD[hd][r], o);
            }
    }
    if (lm == 0) {
        float2* asp = (float2*)as1m;
        float2* adp = (float2*)ad1m;
#pragma unroll
        for (int r = 0; r < 4; ++r) {
            int row = m0 + lq * 4 + r;
            asp[row]           = make_float2(sS[0][r], sS[1][r]);   // pair 0
            asp[N_NODES + row] = make_float2(sS[2][r], sS[3][r]);   // pair 1
            adp[row]           = make_float2(sD[0][r], sD[1][r]);
            adp[N_NODES + row] = make_float2(sD[2][r], sD[3][r]);
        }
    }
}

// ================= GEMM2 (MFMA fp16) + fused attention dots (1 head) =================
__global__ __launch_bounds__(256) void gemm2_mfma(
        const __half* __restrict__ ah, const __half* __restrict__ w2t,
        const float* __restrict__ aws, const float* __restrict__ awd,
        __half* __restrict__ h, float* __restrict__ as2, float* __restrict__ ad2) {
    const int tile = blockIdx.x * 4 + (threadIdx.x >> 6);
    if (tile >= MTILES) return;
    const int lane = threadIdx.x & 63;
    const int m0 = tile * 16, lm = lane & 15, lq = lane >> 4;
    h8 afrag[8];
    const h8* arow = (const h8*)(ah + (size_t)(m0 + lm) * C1 + lq * 8);
#pragma unroll
    for (int kt = 0; kt < 8; ++kt) afrag[kt] = arow[kt * 4];
    f4 acc[8];
#pragma unroll
    for (int nt = 0; nt < 8; ++nt) acc[nt] = (f4){0.f, 0.f, 0.f, 0.f};
#pragma unroll
    for (int nt = 0; nt < 8; ++nt) {
        const h8* brow = (const h8*)(w2t + (size_t)(nt * 16 + lm) * C1 + lq * 8);
#pragma unroll
        for (int kt = 0; kt < 8; ++kt)
            acc[nt] = __builtin_amdgcn_mfma_f32_16x16x32_f16(afrag[kt], brow[kt * 4],
                                                             acc[nt], 0, 0, 0);
    }
    float sS[4] = {0.f, 0.f, 0.f, 0.f}, sD[4] = {0.f, 0.f, 0.f, 0.f};
#pragma unroll
    for (int nt = 0; nt < 8; ++nt) {
        int col = nt * 16 + lm;
        float wa = aws[col], wd = awd[col];
#pragma unroll
        for (int r = 0; r < 4; ++r) {
            float v = acc[nt][r];
            h[(size_t)(m0 + lq * 4 + r) * OUT_DIM + col] = __float2half(v);
            sS[r] += v * wa;
            sD[r] += v * wd;
        }
    }
#pragma unroll
    for (int o = 1; o < 16; o <<= 1) {
#pragma unroll
        for (int r = 0; r < 4; ++r) {
            sS[r] += __shfl_xor(sS[r], o);
            sD[r] += __shfl_xor(sD[r], o);
        }
    }
    if (lm == 0) {
#pragma unroll
        for (int r = 0; r < 4; ++r) {
            int row = m0 + lq * 4 + r;
            as2[row] = sS[r];
            ad2[row] = sD[r];
        }
    }
}

// ================= fused softmax + aggregate, layer 1, HEAD-PAIR SPLIT =================
// (r8 measured-best inner structure; gbase enables the 2-way census split)
__global__ __launch_bounds__(256) void aggregate1_fused(
        const int* __restrict__ rp, const u16* __restrict__ cs16,
        const __half* __restrict__ hpm, const float* __restrict__ as1m,
        const float* __restrict__ ad1m, const float* __restrict__ b1,
        __half* __restrict__ out1h, int gbase) {
    __shared__ int4 stg[8][32];      // [halfwave][edge] = {row byte off, a_h0, a_h1, pad}
    const int vb = blockIdx.x + gbase;
    const int pair = vb & 1, g = vb >> 1;
    const int hw = threadIdx.x >> 5, li = threadIdx.x & 31;
    const int d = g * 8 + hw;
    const int e0 = rp[d], deg = rp[d + 1] - e0;  // deg >= 1 (self-loop)
    const float2* asb = (const float2*)as1m + (size_t)pair * N_NODES;
    const float2 adv = ((const float2*)ad1m)[(size_t)pair * N_NODES + d];
    const char* hb = (const char*)hpm + (size_t)pair * N_NODES * 256;
    const int es = li >> 4, fl = li & 15;
    const int hip = fl >> 3;         // head within pair owning this lane's 8 feats
    const int lbyte = fl * 16;       // 8 fp16 = 16 B; 16 lanes cover the 256-B row
    float acc[8] = {0.f, 0.f, 0.f, 0.f, 0.f, 0.f, 0.f, 0.f};
    float ds0 = 0.f, ds1 = 0.f;
    for (int c0 = 0; c0 < deg; c0 += 32) {
        const int clen = min(32, deg - c0);
        int idx = c0 + li;
        bool valid = idx < deg;
        int s = valid ? (int)cs16[e0 + idx] : 0;
        float2 av = asb[s];
        float x0 = valid ? __expf(leaky(av.x + adv.x)) : 0.f;
        float x1 = valid ? __expf(leaky(av.y + adv.y)) : 0.f;
        stg[hw][li] = make_int4(s << 8, __float_as_int(x0), __float_as_int(x1), 0);
        ds0 += x0; ds1 += x1;
        __builtin_amdgcn_wave_barrier();  // DS in-order per wave; block compiler reordering
        int j = 0;
        for (; j + 8 <= clen; j += 8) {   // 8 edges per iteration, 4 loads in flight
            int4 p0 = stg[hw][j + es];
            int4 p1 = stg[hw][j + 2 + es];
            int4 p2 = stg[hw][j + 4 + es];
            int4 p3 = stg[hw][j + 6 + es];
            h8 v0 = *(const h8*)(hb + p0.x + lbyte);
            h8 v1 = *(const h8*)(hb + p1.x + lbyte);
            h8 v2 = *(const h8*)(hb + p2.x + lbyte);
            h8 v3 = *(const h8*)(hb + p3.x + lbyte);
            fma_mix8(acc, v0, __int_as_float(hip ? p0.z : p0.y));
            fma_mix8(acc, v1, __int_as_float(hip ? p1.z : p1.y));
            fma_mix8(acc, v2, __int_as_float(hip ? p2.z : p2.y));
            fma_mix8(acc, v3, __int_as_float(hip ? p3.z : p3.y));
        }
        for (; j < clen; j += 2) {
            // slots up to 31 always initialized (alpha=0 when invalid) -> safe
            int4 p0 = stg[hw][j + es];
            h8 v0 = *(const h8*)(hb + p0.x + lbyte);
            fma_mix8(acc, v0, __int_as_float(hip ? p0.z : p0.y));
        }
        __builtin_amdgcn_wave_barrier();
    }
    // combine the 2 edge-slot groups (mask 16 stays within the 32-lane half)
#pragma unroll
    for (int f = 0; f < 8; ++f) acc[f] += __shfl_xor(acc[f], 16);
#pragma unroll
    for (int o = 16; o > 0; o >>= 1) {
        ds0 += __shfl_xor(ds0, o);
        ds1 += __shfl_xor(ds1, o);
    }
    if (es == 0) {                   // lanes 0..15 of the half-wave
        float den = hip ? ds1 : ds0;
        float inv = 1.0f / (den + 1e-16f);
        float4 bA = ((const float4*)b1)[pair * 32 + fl * 2];
        float4 bB = ((const float4*)b1)[pair * 32 + fl * 2 + 1];
        h8 o;
        o[0] = (_Float16)elu(acc[0] * inv + bA.x);
        o[1] = (_Float16)elu(acc[1] * inv + bA.y);
        o[2] = (_Float16)elu(acc[2] * inv + bA.z);
        o[3] = (_Float16)elu(acc[3] * inv + bA.w);
        o[4] = (_Float16)elu(acc[4] * inv + bB.x);
        o[5] = (_Float16)elu(acc[5] * inv + bB.y);
        o[6] = (_Float16)elu(acc[6] * inv + bB.z);
        o[7] = (_Float16)elu(acc[7] * inv + bB.w);
        *(h8*)((char*)out1h + (size_t)d * 512 + pair * 256 + lbyte) = o;
    }
}

// ================= fused softmax + aggregate + bias + L2-normalize, layer 2 ======
// (r8 measured-best; kept WHOLE so the census finally shows its true duration)
__global__ __launch_bounds__(256) void aggregate2_fused(
        const int* __restrict__ rp, const u16* __restrict__ cs16,
        const __half* __restrict__ h2h, const float* __restrict__ as2,
        const float* __restrict__ ad2, const float* __restrict__ b2,
        float* __restrict__ out) {
    __shared__ int2 stg[8][32];      // [halfwave][edge] = {row byte offset, alpha bits}
    const int hw = threadIdx.x >> 5, li = threadIdx.x & 31;
    const int d = blockIdx.x * 8 + hw;
    const int e0 = rp[d], deg = rp[d + 1] - e0;
    const float adv = ad2[d];
    const int q = li >> 4, lo = li & 15;
    const int lbyte = lo * 16;       // 8 fp16
    const char* hbase = (const char*)h2h;
    float acc[8] = {0.f, 0.f, 0.f, 0.f, 0.f, 0.f, 0.f, 0.f};
    float dsum = 0.f;
    for (int c0 = 0; c0 < deg; c0 += 32) {
        const int clen = min(32, deg - c0);
        int idx = c0 + li;
        bool valid = idx < deg;
        int s = valid ? (int)cs16[e0 + idx] : 0;
        float xv = valid ? __expf(leaky(as2[s] + adv)) : 0.f;
        stg[hw][li] = make_int2(s << 8, __float_as_int(xv));  // row = 256 B
        dsum += xv;
        __builtin_amdgcn_wave_barrier();
        int j = 0;
        for (; j + 8 <= clen; j += 8) {   // 8 edges per iteration, 4 loads in flight
            int2 p0 = stg[hw][j + q];
            int2 p1 = stg[hw][j + 2 + q];
            int2 p2 = stg[hw][j + 4 + q];
            int2 p3 = stg[hw][j + 6 + q];
            h8 v0 = *(const h8*)(hbase + p0.x + lbyte);
            h8 v1 = *(const h8*)(hbase + p1.x + lbyte);
            h8 v2 = *(const h8*)(hbase + p2.x + lbyte);
            h8 v3 = *(const h8*)(hbase + p3.x + lbyte);
            fma_mix8(acc, v0, __int_as_float(p0.y));
            fma_mix8(acc, v1, __int_as_float(p1.y));
            fma_mix8(acc, v2, __int_as_float(p2.y));
            fma_mix8(acc, v3, __int_as_float(p3.y));
        }
        for (; j < clen; j += 2) {
            int2 p0 = stg[hw][j + q];
            h8 v0 = *(const h8*)(hbase + p0.x + lbyte);
            fma_mix8(acc, v0, __int_as_float(p0.y));
        }
        __builtin_amdgcn_wave_barrier();
    }
#pragma unroll
    for (int f = 0; f < 8; ++f) acc[f] += __shfl_xor(acc[f], 16);  // combine q=0/1
#pragma unroll
    for (int o = 16; o > 0; o >>= 1) dsum += __shfl_xor(dsum, o);
    if (q == 0) {
        float inv = 1.0f / (dsum + 1e-16f);
        float4 bA = ((const float4*)b2)[lo * 2];
        float4 bB = ((const float4*)b2)[lo * 2 + 1];
        float v0 = acc[0] * inv + bA.x, v1 = acc[1] * inv + bA.y;
        float v2 = acc[2] * inv + bA.z, v3 = acc[3] * inv + bA.w;
        float v4 = acc[4] * inv + bB.x, v5 = acc[5] * inv + bB.y;
        float v6 = acc[6] * inv + bB.z, v7 = acc[7] * inv + bB.w;
        float ss = v0 * v0 + v1 * v1 + v2 * v2 + v3 * v3 +
                   v4 * v4 + v5 * v5 + v6 * v6 + v7 * v7;
#pragma unroll
        for (int o = 1; o < 16; o <<= 1) ss += __shfl_xor(ss, o);  // lanes lo 0-15 group
        float sc = 1.0f / fmaxf(sqrtf(ss), 1e-12f);
        float4* orow = (float4*)((char*)out + (size_t)d * 512 + lo * 32);
        orow[0] = make_float4(v0 * sc, v1 * sc, v2 * sc, v3 * sc);
        orow[1] = make_float4(v4 * sc, v5 * sc, v6 * sc, v7 * sc);
    }
}

extern "C" void kernel_launch(void* const* d_in, const int* in_sizes, int n_in,
                              void* d_out, int out_size, void* d_ws, size_t ws_size,
                              hipStream_t stream) {
    const float* x     = (const float*)d_in[0];
    const int*   edge  = (const int*)d_in[1];
    const int*   src   = edge;
    const int*   dst   = edge + N_EDGES;
    const float* W1    = (const float*)d_in[2];
    const float* aw_s1 = (const float*)d_in[3];
    const float* aw_d1 = (const float*)d_in[4];
    const float* b1    = (const float*)d_in[5];
    const float* W2    = (const float*)d_in[6];
    const float* aw_s2 = (const float*)d_in[7];
    const float* aw_d2 = (const float*)d_in[8];
    const float* b2    = (const float*)d_in[9];
    float* out = (float*)d_out;

    // ---- workspace layout ----
    char* ws = (char*)d_ws;
    size_t off = 0;
    auto alloc = [&](size_t bytes) {
        void* p = ws + off;
        off += (bytes + 255) & ~(size_t)255;
        return p;
    };
    u16*    cs16    = (u16*)alloc((size_t)ET * 2);                   // 1.7 MB
    u16*    lrank16 = (u16*)alloc((size_t)N_EDGES * 2);              // 1.6 MB
    u16*    cnt_mat = (u16*)alloc((size_t)HB * N_NODES * 2);         // 6.4 MB
    u16*    boff    = (u16*)alloc((size_t)HB * N_NODES * 2);         // 6.4 MB
    int*    rp      = (int*)alloc((size_t)(N_NODES + 1) * 4);
    int*    lscan   = (int*)alloc((size_t)NSCB * SCAN_B * 4);
    int*    bsum    = (int*)alloc((size_t)NSCB * 4);
    float*  as1     = (float*)alloc((size_t)N_NODES * HEADS * 4);    // pair-major float2
    float*  ad1     = (float*)alloc((size_t)N_NODES * HEADS * 4);    // pair-major float2
    float*  as2     = (float*)alloc((size_t)N_NODES * 4);
    float*  ad2     = (float*)alloc((size_t)N_NODES * 4);
    __half* w1t     = (__half*)alloc((size_t)IN_DIM * C1 * 2);
    __half* w2t     = (__half*)alloc((size_t)C1 * OUT_DIM * 2);
    __half* hpm     = (__half*)alloc((size_t)N_NODES * C1 * 2);      // 25.6 MB pair-major (reused as h2h)
    __half* out1h   = (__half*)alloc((size_t)N_NODES * C1 * 2);      // 25.6 MB node-major
    __half* h2h     = hpm;  // layer-1 pair tables dead after aggregate1
    (void)off;

    // No memset needed: every ws buffer is fully written before first read.

    // ---- CSR build: hist(+transpose, 256-block) -> scan -> fused scatter||gemm1 ----
    hist_kernel<<<HB * 4, 256, 0, stream>>>(W1, W2, w1t, w2t, dst, cnt_mat, lrank16);
    scan_local<<<NSCB, SCAN_B, 0, stream>>>(cnt_mat, boff, lscan, bsum);
    scan_final<<<NSCB, SCAN_B, 0, stream>>>(lscan, bsum, rp);
    // split into 2 half-dispatches (census: exposes hidden kernels in top-5)
    gemm1_scatter<<<882, 256, 0, stream>>>(x, w1t, aw_s1, aw_d1, hpm, as1, ad1,
                                           src, dst, lrank16, boff, rp, cs16, 0);
    gemm1_scatter<<<882, 256, 0, stream>>>(x, w1t, aw_s1, aw_d1, hpm, as1, ad1,
                                           src, dst, lrank16, boff, rp, cs16, 882);

    // ---- layer 1 aggregate (2 half-dispatches for census) ----
    aggregate1_fused<<<6250, 256, 0, stream>>>(rp, cs16, hpm, as1, ad1, b1, out1h, 0);
    aggregate1_fused<<<6250, 256, 0, stream>>>(rp, cs16, hpm, as1, ad1, b1, out1h, 6250);

    // ---- layer 2 ----
    gemm2_mfma<<<(MTILES + 3) / 4, 256, 0, stream>>>(out1h, w2t, aw_s2, aw_d2, h2h, as2, ad2);
    aggregate2_fused<<<N_NODES / 8, 256, 0, stream>>>(rp, cs16, h2h, as2, ad2, b2, out);
}

// Round 14
// 285.572 us; speedup vs baseline: 1.0611x; 1.0611x over previous
//
#include <hip/hip_runtime.h>
#include <hip/hip_fp16.h>
#include <math.h>

#define N_NODES 50000
#define N_EDGES 800000
#define ET (N_EDGES + N_NODES)   // edges + self-loops
#define IN_DIM 128
#define HID 64
#define HEADS 4
#define C1 (HEADS * HID)         // 256
#define OUT_DIM 128
#define NEG_SLOPE 0.2f
#define MTILES 3125              // 50000 / 16 row-tiles
#define G1GRP 782                // ceil(MTILES/4) gemm1 tile groups
#define SCAN_B 1024
#define NSCB 49                  // ceil(50000/1024)
#define HB 64                    // histogram edge-segments
#define EPB (N_EDGES / HB)       // 12500 edges per segment (EPB/4 = 3125)
#define NQ (N_NODES / 4)         // 12500 nodes per quarter

typedef _Float16 h8 __attribute__((ext_vector_type(8)));
typedef float f4 __attribute__((ext_vector_type(4)));
typedef unsigned short u16;

__device__ __forceinline__ float leaky(float v) { return fmaxf(v, NEG_SLOPE * v); }
__device__ __forceinline__ float elu(float v) { return v > 0.0f ? v : expm1f(v); }

// One v_fma_mix_f32 per feature: acc.f32 += h.f16 * w.f32 (no extract/convert insts)
__device__ __forceinline__ void fma_mix8(float* acc, h8 v, float w) {
    union { h8 h; int i[4]; } u; u.h = v;
#pragma unroll
    for (int k = 0; k < 4; ++k) {
        asm("v_fma_mix_f32 %0, %1, %2, %0 op_sel:[0,0,0] op_sel_hi:[1,0,0]"
            : "+v"(acc[2 * k]) : "v"(u.i[k]), "v"(w));
        asm("v_fma_mix_f32 %0, %1, %2, %0 op_sel:[1,0,0] op_sel_hi:[1,0,0]"
            : "+v"(acc[2 * k + 1]) : "v"(u.i[k]), "v"(w));
    }
}

// ====== hist: 256 blocks = 64 edge-segments x 4 node-quarters, 25 KB LDS each ====
__global__ __launch_bounds__(256) void hist_kernel(
        const float* __restrict__ W1, const float* __restrict__ W2,
        __half* __restrict__ w1t, __half* __restrict__ w2t,
        const int* __restrict__ dst, u16* __restrict__ cnt_mat,
        u16* __restrict__ lrank16) {
    __shared__ unsigned pk[NQ / 2];   // 6250 u32 = 25 KB (12.5k nodes, 2 per u32)
    const int b = blockIdx.x >> 2;    // edge segment
    const int qd = blockIdx.x & 3;    // node quarter
    const int t = threadIdx.x;
    {   // weight transpose spread over the 256 blocks (one element per thread)
        int i = blockIdx.x * 256 + t;
        if (i < IN_DIM * C1) {
            int k1 = i >> 8, n1 = i & 255;
            w1t[n1 * IN_DIM + k1] = __float2half(W1[i]);
            int k2 = i >> 7, n2 = i & 127;
            w2t[n2 * C1 + k2] = __float2half(W2[i]);
        }
    }
    const int e0 = b * EPB;
    const int nbase = qd * NQ;
    for (int i = t; i < NQ / 2; i += 256) pk[i] = 0;
    __syncthreads();
    const int4* d4p = (const int4*)(dst + e0);
    for (int k4 = t; k4 < EPB / 4; k4 += 256) {   // 13 iterations
        int4 d4 = d4p[k4];
        int dd0 = d4.x - nbase, dd1 = d4.y - nbase;
        int dd2 = d4.z - nbase, dd3 = d4.w - nbase;
        if ((unsigned)dd0 < (unsigned)NQ) {
            unsigned r = atomicAdd(&pk[dd0 >> 1], (dd0 & 1) ? 65536u : 1u);
            lrank16[e0 + k4 * 4 + 0] = (u16)((dd0 & 1) ? (r >> 16) : (r & 0xffffu));
        }
        if ((unsigned)dd1 < (unsigned)NQ) {
            unsigned r = atomicAdd(&pk[dd1 >> 1], (dd1 & 1) ? 65536u : 1u);
            lrank16[e0 + k4 * 4 + 1] = (u16)((dd1 & 1) ? (r >> 16) : (r & 0xffffu));
        }
        if ((unsigned)dd2 < (unsigned)NQ) {
            unsigned r = atomicAdd(&pk[dd2 >> 1], (dd2 & 1) ? 65536u : 1u);
            lrank16[e0 + k4 * 4 + 2] = (u16)((dd2 & 1) ? (r >> 16) : (r & 0xffffu));
        }
        if ((unsigned)dd3 < (unsigned)NQ) {
            unsigned r = atomicAdd(&pk[dd3 >> 1], (dd3 & 1) ? 65536u : 1u);
            lrank16[e0 + k4 * 4 + 3] = (u16)((dd3 & 1) ? (r >> 16) : (r & 0xffffu));
        }
    }
    __syncthreads();
    // dump this (segment, quarter)'s counts: u16 pair layout, 4-B aligned
    unsigned* crow = (unsigned*)(cnt_mat + (size_t)b * N_NODES + nbase);
    for (int i = t; i < NQ / 2; i += 256) crow[i] = pk[i];
}

// ====== CSR scan: per-node total over 64 block-counts + exclusive block offsets ====
__global__ void scan_local(const u16* __restrict__ cnt_mat, u16* __restrict__ boff,
                           int* __restrict__ lscan, int* __restrict__ bsum) {
    __shared__ int wsum[16];
    const int t = threadIdx.x, lane = t & 63, wv = t >> 6;
    int idx = blockIdx.x * SCAN_B + t;
    int run = 0;
    if (idx < N_NODES) {
#pragma unroll 8
        for (int b = 0; b < HB; ++b) {            // coalesced per-b column walk
            u16 c = cnt_mat[(size_t)b * N_NODES + idx];
            boff[(size_t)b * N_NODES + idx] = (u16)run;
            run += c;
        }
    }
    int v = (idx < N_NODES) ? run + 1 : 0;        // +1 = self-loop
    int sc = v;
#pragma unroll
    for (int o = 1; o < 64; o <<= 1) {
        int u = __shfl_up(sc, o);
        if (lane >= o) sc += u;
    }
    if (lane == 63) wsum[wv] = sc;
    __syncthreads();
    if (t == 0) {
        int run2 = 0;
#pragma unroll
        for (int w = 0; w < 16; ++w) { int s = wsum[w]; wsum[w] = run2; run2 += s; }
        bsum[blockIdx.x] = run2;
    }
    __syncthreads();
    if (idx < N_NODES) lscan[idx] = sc + wsum[wv];  // inclusive within block
}

// ====== scan_final with inlined bsum prefix ======
__global__ void scan_final(const int* __restrict__ lscan, const int* __restrict__ bsum,
                           int* __restrict__ rp) {
    __shared__ int base;
    if (threadIdx.x == 0) {
        int s = 0;
        for (int b = 0; b < blockIdx.x; ++b) s += bsum[b];   // <= 48 loads
        base = s;
    }
    __syncthreads();
    int idx = blockIdx.x * SCAN_B + threadIdx.x;
    if (idx == 0) rp[0] = 0;
    if (idx >= N_NODES) return;
    rp[idx + 1] = lscan[idx] + base;
}

// ========= FUSED: atomic-free scatter (8 edges/thread) || GEMM1 =========
// Interleave 4 gemm1 : 3 scatter over 1372 blocks. Scatter role: 2 independent
// 4-edge groups per thread (doubles outstanding requests — it ran latency-bound
// at 28% occupancy in r12). Self-loop tail folded in after the edge range.
__global__ __launch_bounds__(256) void gemm1_scatter(
        const float* __restrict__ x, const __half* __restrict__ w1t,
        const float* __restrict__ aws, const float* __restrict__ awd,
        __half* __restrict__ hpm, float* __restrict__ as1m, float* __restrict__ ad1m,
        const int* __restrict__ src, const int* __restrict__ dst,
        const u16* __restrict__ lrank16, const u16* __restrict__ boff,
        const int* __restrict__ rp, u16* __restrict__ cs16) {
    const int q7 = blockIdx.x / 7, r7 = blockIdx.x % 7;
    if (r7 >= 4) {
        // ---- scatter role: sub-block si in [0, 588); 8 edges per thread ----
        int si = q7 * 3 + (r7 - 4);
        int tid = si * 256 + threadIdx.x;
        if (tid < N_EDGES / 8) {
#pragma unroll
            for (int gg = 0; gg < 2; ++gg) {
                int g = tid * 2 + gg;                 // 4-edge group index
                const int b = g / (EPB / 4);          // hist segment of this group
                const u16* bo = boff + (size_t)b * N_NODES;
                int4 s4 = ((const int4*)src)[g];
                int4 d4 = ((const int4*)dst)[g];
                ushort4 r4 = ((const ushort4*)lrank16)[g];
                cs16[rp[d4.x] + (int)bo[d4.x] + (int)r4.x] = (u16)s4.x;
                cs16[rp[d4.y] + (int)bo[d4.y] + (int)r4.y] = (u16)s4.y;
                cs16[rp[d4.z] + (int)bo[d4.z] + (int)r4.z] = (u16)s4.z;
                cs16[rp[d4.w] + (int)bo[d4.w] + (int)r4.w] = (u16)s4.w;
            }
        } else {
            int d = tid - N_EDGES / 8;
            if (d < N_NODES) cs16[rp[d + 1] - 1] = (u16)d;   // self-loop in last slot
        }
        return;
    }
    // ---- gemm1 role: group g in [0, G1GRP), 4 waves -> 4 row-tiles ----
    const int g = q7 * 4 + r7;
    const int tile = g * 4 + (threadIdx.x >> 6);
    if (tile >= MTILES) return;
    const int lane = threadIdx.x & 63;
    const int m0 = tile * 16, lm = lane & 15, lq = lane >> 4;
    h8 afrag[4];
    const float4* xrow = (const float4*)(x + (size_t)(m0 + lm) * IN_DIM + lq * 8);
#pragma unroll
    for (int kt = 0; kt < 4; ++kt) {
        float4 a = xrow[kt * 8];
        float4 b = xrow[kt * 8 + 1];
        union { h8 v; __half2 p[4]; } u;
        u.p[0] = __floats2half2_rn(a.x, a.y);
        u.p[1] = __floats2half2_rn(a.z, a.w);
        u.p[2] = __floats2half2_rn(b.x, b.y);
        u.p[3] = __floats2half2_rn(b.z, b.w);
        afrag[kt] = u.v;
    }
    f4 acc[16];
#pragma unroll
    for (int nt = 0; nt < 16; ++nt) acc[nt] = (f4){0.f, 0.f, 0.f, 0.f};
#pragma unroll
    for (int nt = 0; nt < 16; ++nt) {
        const h8* brow = (const h8*)(w1t + (size_t)(nt * 16 + lm) * IN_DIM + lq * 8);
#pragma unroll
        for (int kt = 0; kt < 4; ++kt)
            acc[nt] = __builtin_amdgcn_mfma_f32_16x16x32_f16(afrag[kt], brow[kt * 4],
                                                             acc[nt], 0, 0, 0);
    }
    float sS[4][4] = {{0.f}}, sD[4][4] = {{0.f}};
#pragma unroll
    for (int nt = 0; nt < 16; ++nt) {
        int col = nt * 16 + lm;
        float wa = aws[col], wd = awd[col];
        int hd = nt >> 2;           // head = col >> 6
        int pr = nt >> 3;           // pair = col >> 7
        int cip = col & 127;        // col within pair row
#pragma unroll
        for (int r = 0; r < 4; ++r) {
            float v = acc[nt][r];
            hpm[((size_t)pr * N_NODES + (m0 + lq * 4 + r)) * 128 + cip] = __float2half(v);
            sS[hd][r] += v * wa;
            sD[hd][r] += v * wd;
        }
    }
#pragma unroll
    for (int o = 1; o < 16; o <<= 1) {
#pragma unroll
        for (int hd = 0; hd < 4; ++hd)
#pragma unroll
            for (int r = 0; r < 4; ++r) {
                sS[hd][r] += __shfl_xor(sS[hd][r], o);
                sD[hd][r] += __shfl_xor(sD[hd][r], o);
            }
    }
    if (lm == 0) {
        float2* asp = (float2*)as1m;
        float2* adp = (float2*)ad1m;
#pragma unroll
        for (int r = 0; r < 4; ++r) {
            int row = m0 + lq * 4 + r;
            asp[row]           = make_float2(sS[0][r], sS[1][r]);   // pair 0
            asp[N_NODES + row] = make_float2(sS[2][r], sS[3][r]);   // pair 1
            adp[row]           = make_float2(sD[0][r], sD[1][r]);
            adp[N_NODES + row] = make_float2(sD[2][r], sD[3][r]);
        }
    }
}

// ================= GEMM2 (MFMA fp16) + fused attention dots (1 head) =================
__global__ __launch_bounds__(256) void gemm2_mfma(
        const __half* __restrict__ ah, const __half* __restrict__ w2t,
        const float* __restrict__ aws, const float* __restrict__ awd,
        __half* __restrict__ h, float* __restrict__ as2, float* __restrict__ ad2) {
    const int tile = blockIdx.x * 4 + (threadIdx.x >> 6);
    if (tile >= MTILES) return;
    const int lane = threadIdx.x & 63;
    const int m0 = tile * 16, lm = lane & 15, lq = lane >> 4;
    h8 afrag[8];
    const h8* arow = (const h8*)(ah + (size_t)(m0 + lm) * C1 + lq * 8);
#pragma unroll
    for (int kt = 0; kt < 8; ++kt) afrag[kt] = arow[kt * 4];
    f4 acc[8];
#pragma unroll
    for (int nt = 0; nt < 8; ++nt) acc[nt] = (f4){0.f, 0.f, 0.f, 0.f};
#pragma unroll
    for (int nt = 0; nt < 8; ++nt) {
        const h8* brow = (const h8*)(w2t + (size_t)(nt * 16 + lm) * C1 + lq * 8);
#pragma unroll
        for (int kt = 0; kt < 8; ++kt)
            acc[nt] = __builtin_amdgcn_mfma_f32_16x16x32_f16(afrag[kt], brow[kt * 4],
                                                             acc[nt], 0, 0, 0);
    }
    float sS[4] = {0.f, 0.f, 0.f, 0.f}, sD[4] = {0.f, 0.f, 0.f, 0.f};
#pragma unroll
    for (int nt = 0; nt < 8; ++nt) {
        int col = nt * 16 + lm;
        float wa = aws[col], wd = awd[col];
#pragma unroll
        for (int r = 0; r < 4; ++r) {
            float v = acc[nt][r];
            h[(size_t)(m0 + lq * 4 + r) * OUT_DIM + col] = __float2half(v);
            sS[r] += v * wa;
            sD[r] += v * wd;
        }
    }
#pragma unroll
    for (int o = 1; o < 16; o <<= 1) {
#pragma unroll
        for (int r = 0; r < 4; ++r) {
            sS[r] += __shfl_xor(sS[r], o);
            sD[r] += __shfl_xor(sD[r], o);
        }
    }
    if (lm == 0) {
#pragma unroll
        for (int r = 0; r < 4; ++r) {
            int row = m0 + lq * 4 + r;
            as2[row] = sS[r];
            ad2[row] = sD[r];
        }
    }
}

// ================= fused softmax + aggregate, layer 1, HEAD-PAIR SPLIT =================
// (r8 measured-best: 8 edges/iter, 4 loads in flight; u16 cs; single dispatch)
__global__ __launch_bounds__(256) void aggregate1_fused(
        const int* __restrict__ rp, const u16* __restrict__ cs16,
        const __half* __restrict__ hpm, const float* __restrict__ as1m,
        const float* __restrict__ ad1m, const float* __restrict__ b1,
        __half* __restrict__ out1h) {
    __shared__ int4 stg[8][32];      // [halfwave][edge] = {row byte off, a_h0, a_h1, pad}
    const int pair = blockIdx.x & 1, g = blockIdx.x >> 1;
    const int hw = threadIdx.x >> 5, li = threadIdx.x & 31;
    const int d = g * 8 + hw;
    const int e0 = rp[d], deg = rp[d + 1] - e0;  // deg >= 1 (self-loop)
    const float2* asb = (const float2*)as1m + (size_t)pair * N_NODES;
    const float2 adv = ((const float2*)ad1m)[(size_t)pair * N_NODES + d];
    const char* hb = (const char*)hpm + (size_t)pair * N_NODES * 256;
    const int es = li >> 4, fl = li & 15;
    const int hip = fl >> 3;         // head within pair owning this lane's 8 feats
    const int lbyte = fl * 16;       // 8 fp16 = 16 B; 16 lanes cover the 256-B row
    float acc[8] = {0.f, 0.f, 0.f, 0.f, 0.f, 0.f, 0.f, 0.f};
    float ds0 = 0.f, ds1 = 0.f;
    for (int c0 = 0; c0 < deg; c0 += 32) {
        const int clen = min(32, deg - c0);
        int idx = c0 + li;
        bool valid = idx < deg;
        int s = valid ? (int)cs16[e0 + idx] : 0;
        float2 av = asb[s];
        float x0 = valid ? __expf(leaky(av.x + adv.x)) : 0.f;
        float x1 = valid ? __expf(leaky(av.y + adv.y)) : 0.f;
        stg[hw][li] = make_int4(s << 8, __float_as_int(x0), __float_as_int(x1), 0);
        ds0 += x0; ds1 += x1;
        __builtin_amdgcn_wave_barrier();  // DS in-order per wave; block compiler reordering
        int j = 0;
        for (; j + 8 <= clen; j += 8) {   // 8 edges per iteration, 4 loads in flight
            int4 p0 = stg[hw][j + es];
            int4 p1 = stg[hw][j + 2 + es];
            int4 p2 = stg[hw][j + 4 + es];
            int4 p3 = stg[hw][j + 6 + es];
            h8 v0 = *(const h8*)(hb + p0.x + lbyte);
            h8 v1 = *(const h8*)(hb + p1.x + lbyte);
            h8 v2 = *(const h8*)(hb + p2.x + lbyte);
            h8 v3 = *(const h8*)(hb + p3.x + lbyte);
            fma_mix8(acc, v0, __int_as_float(hip ? p0.z : p0.y));
            fma_mix8(acc, v1, __int_as_float(hip ? p1.z : p1.y));
            fma_mix8(acc, v2, __int_as_float(hip ? p2.z : p2.y));
            fma_mix8(acc, v3, __int_as_float(hip ? p3.z : p3.y));
        }
        for (; j < clen; j += 2) {
            // slots up to 31 always initialized (alpha=0 when invalid) -> safe
            int4 p0 = stg[hw][j + es];
            h8 v0 = *(const h8*)(hb + p0.x + lbyte);
            fma_mix8(acc, v0, __int_as_float(hip ? p0.z : p0.y));
        }
        __builtin_amdgcn_wave_barrier();
    }
    // combine the 2 edge-slot groups (mask 16 stays within the 32-lane half)
#pragma unroll
    for (int f = 0; f < 8; ++f) acc[f] += __shfl_xor(acc[f], 16);
#pragma unroll
    for (int o = 16; o > 0; o >>= 1) {
        ds0 += __shfl_xor(ds0, o);
        ds1 += __shfl_xor(ds1, o);
    }
    if (es == 0) {                   // lanes 0..15 of the half-wave
        float den = hip ? ds1 : ds0;
        float inv = 1.0f / (den + 1e-16f);
        float4 bA = ((const float4*)b1)[pair * 32 + fl * 2];
        float4 bB = ((const float4*)b1)[pair * 32 + fl * 2 + 1];
        h8 o;
        o[0] = (_Float16)elu(acc[0] * inv + bA.x);
        o[1] = (_Float16)elu(acc[1] * inv + bA.y);
        o[2] = (_Float16)elu(acc[2] * inv + bA.z);
        o[3] = (_Float16)elu(acc[3] * inv + bA.w);
        o[4] = (_Float16)elu(acc[4] * inv + bB.x);
        o[5] = (_Float16)elu(acc[5] * inv + bB.y);
        o[6] = (_Float16)elu(acc[6] * inv + bB.z);
        o[7] = (_Float16)elu(acc[7] * inv + bB.w);
        *(h8*)((char*)out1h + (size_t)d * 512 + pair * 256 + lbyte) = o;
    }
}

// ================= fused softmax + aggregate + bias + L2-normalize, layer 2 ======
// (r8 measured-best: 8 edges/iter, 4 loads in flight; u16 cs)
__global__ __launch_bounds__(256) void aggregate2_fused(
        const int* __restrict__ rp, const u16* __restrict__ cs16,
        const __half* __restrict__ h2h, const float* __restrict__ as2,
        const float* __restrict__ ad2, const float* __restrict__ b2,
        float* __restrict__ out) {
    __shared__ int2 stg[8][32];      // [halfwave][edge] = {row byte offset, alpha bits}
    const int hw = threadIdx.x >> 5, li = threadIdx.x & 31;
    const int d = blockIdx.x * 8 + hw;
    const int e0 = rp[d], deg = rp[d + 1] - e0;
    const float adv = ad2[d];
    const int q = li >> 4, lo = li & 15;
    const int lbyte = lo * 16;       // 8 fp16
    const char* hbase = (const char*)h2h;
    float acc[8] = {0.f, 0.f, 0.f, 0.f, 0.f, 0.f, 0.f, 0.f};
    float dsum = 0.f;
    for (int c0 = 0; c0 < deg; c0 += 32) {
        const int clen = min(32, deg - c0);
        int idx = c0 + li;
        bool valid = idx < deg;
        int s = valid ? (int)cs16[e0 + idx] : 0;
        float xv = valid ? __expf(leaky(as2[s] + adv)) : 0.f;
        stg[hw][li] = make_int2(s << 8, __float_as_int(xv));  // row = 256 B
        dsum += xv;
        __builtin_amdgcn_wave_barrier();
        int j = 0;
        for (; j + 8 <= clen; j += 8) {   // 8 edges per iteration, 4 loads in flight
            int2 p0 = stg[hw][j + q];
            int2 p1 = stg[hw][j + 2 + q];
            int2 p2 = stg[hw][j + 4 + q];
            int2 p3 = stg[hw][j + 6 + q];
            h8 v0 = *(const h8*)(hbase + p0.x + lbyte);
            h8 v1 = *(const h8*)(hbase + p1.x + lbyte);
            h8 v2 = *(const h8*)(hbase + p2.x + lbyte);
            h8 v3 = *(const h8*)(hbase + p3.x + lbyte);
            fma_mix8(acc, v0, __int_as_float(p0.y));
            fma_mix8(acc, v1, __int_as_float(p1.y));
            fma_mix8(acc, v2, __int_as_float(p2.y));
            fma_mix8(acc, v3, __int_as_float(p3.y));
        }
        for (; j < clen; j += 2) {
            int2 p0 = stg[hw][j + q];
            h8 v0 = *(const h8*)(hbase + p0.x + lbyte);
            fma_mix8(acc, v0, __int_as_float(p0.y));
        }
        __builtin_amdgcn_wave_barrier();
    }
#pragma unroll
    for (int f = 0; f < 8; ++f) acc[f] += __shfl_xor(acc[f], 16);  // combine q=0/1
#pragma unroll
    for (int o = 16; o > 0; o >>= 1) dsum += __shfl_xor(dsum, o);
    if (q == 0) {
        float inv = 1.0f / (dsum + 1e-16f);
        float4 bA = ((const float4*)b2)[lo * 2];
        float4 bB = ((const float4*)b2)[lo * 2 + 1];
        float v0 = acc[0] * inv + bA.x, v1 = acc[1] * inv + bA.y;
        float v2 = acc[2] * inv + bA.z, v3 = acc[3] * inv + bA.w;
        float v4 = acc[4] * inv + bB.x, v5 = acc[5] * inv + bB.y;
        float v6 = acc[6] * inv + bB.z, v7 = acc[7] * inv + bB.w;
        float ss = v0 * v0 + v1 * v1 + v2 * v2 + v3 * v3 +
                   v4 * v4 + v5 * v5 + v6 * v6 + v7 * v7;
#pragma unroll
        for (int o = 1; o < 16; o <<= 1) ss += __shfl_xor(ss, o);  // lanes lo 0-15 group
        float sc = 1.0f / fmaxf(sqrtf(ss), 1e-12f);
        float4* orow = (float4*)((char*)out + (size_t)d * 512 + lo * 32);
        orow[0] = make_float4(v0 * sc, v1 * sc, v2 * sc, v3 * sc);
        orow[1] = make_float4(v4 * sc, v5 * sc, v6 * sc, v7 * sc);
    }
}

extern "C" void kernel_launch(void* const* d_in, const int* in_sizes, int n_in,
                              void* d_out, int out_size, void* d_ws, size_t ws_size,
                              hipStream_t stream) {
    const float* x     = (const float*)d_in[0];
    const int*   edge  = (const int*)d_in[1];
    const int*   src   = edge;
    const int*   dst   = edge + N_EDGES;
    const float* W1    = (const float*)d_in[2];
    const float* aw_s1 = (const float*)d_in[3];
    const float* aw_d1 = (const float*)d_in[4];
    const float* b1    = (const float*)d_in[5];
    const float* W2    = (const float*)d_in[6];
    const float* aw_s2 = (const float*)d_in[7];
    const float* aw_d2 = (const float*)d_in[8];
    const float* b2    = (const float*)d_in[9];
    float* out = (float*)d_out;

    // ---- workspace layout ----
    char* ws = (char*)d_ws;
    size_t off = 0;
    auto alloc = [&](size_t bytes) {
        void* p = ws + off;
        off += (bytes + 255) & ~(size_t)255;
        return p;
    };
    u16*    cs16    = (u16*)alloc((size_t)ET * 2);                   // 1.7 MB
    u16*    lrank16 = (u16*)alloc((size_t)N_EDGES * 2);              // 1.6 MB
    u16*    cnt_mat = (u16*)alloc((size_t)HB * N_NODES * 2);         // 6.4 MB
    u16*    boff    = (u16*)alloc((size_t)HB * N_NODES * 2);         // 6.4 MB
    int*    rp      = (int*)alloc((size_t)(N_NODES + 1) * 4);
    int*    lscan   = (int*)alloc((size_t)NSCB * SCAN_B * 4);
    int*    bsum    = (int*)alloc((size_t)NSCB * 4);
    float*  as1     = (float*)alloc((size_t)N_NODES * HEADS * 4);    // pair-major float2
    float*  ad1     = (float*)alloc((size_t)N_NODES * HEADS * 4);    // pair-major float2
    float*  as2     = (float*)alloc((size_t)N_NODES * 4);
    float*  ad2     = (float*)alloc((size_t)N_NODES * 4);
    __half* w1t     = (__half*)alloc((size_t)IN_DIM * C1 * 2);
    __half* w2t     = (__half*)alloc((size_t)C1 * OUT_DIM * 2);
    __half* hpm     = (__half*)alloc((size_t)N_NODES * C1 * 2);      // 25.6 MB pair-major (reused as h2h)
    __half* out1h   = (__half*)alloc((size_t)N_NODES * C1 * 2);      // 25.6 MB node-major
    __half* h2h     = hpm;  // layer-1 pair tables dead after aggregate1
    (void)off;

    // No memset needed: every ws buffer is fully written before first read.

    // ---- CSR build: hist(+transpose, 256-block) -> scan -> fused scatter||gemm1 ----
    hist_kernel<<<HB * 4, 256, 0, stream>>>(W1, W2, w1t, w2t, dst, cnt_mat, lrank16);
    scan_local<<<NSCB, SCAN_B, 0, stream>>>(cnt_mat, boff, lscan, bsum);
    scan_final<<<NSCB, SCAN_B, 0, stream>>>(lscan, bsum, rp);
    gemm1_scatter<<<196 * 7, 256, 0, stream>>>(x, w1t, aw_s1, aw_d1, hpm, as1, ad1,
                                               src, dst, lrank16, boff, rp, cs16);

    // ---- layer 1 aggregate ----
    aggregate1_fused<<<(N_NODES / 8) * 2, 256, 0, stream>>>(rp, cs16, hpm, as1, ad1, b1, out1h);

    // ---- layer 2 ----
    gemm2_mfma<<<(MTILES + 3) / 4, 256, 0, stream>>>(out1h, w2t, aw_s2, aw_d2, h2h, as2, ad2);
    aggregate2_fused<<<N_NODES / 8, 256, 0, stream>>>(rp, cs16, h2h, as2, ad2, b2, out);
}